// Round 14
// baseline (193.750 us; speedup 1.0000x reference)
//
#include <hip/hip_runtime.h>

// GeometryTransformation: backproject(theta=0) -> 2x resblock(conv3d 16->16 3^3,
// InstanceNorm, ReLU, residual) -> forward-project at theta in {0, pi/2}.
//
// Round-23 (on R22, 172.9us): interior DP=4. Interior block owns FOUR
// d-slices (stage 6 planes x 18 rows x 20 = 8.6KB; block LDS 18.1KB, mini
// still binds occupancy): wsl weight re-reads 4.7 -> 2.35 MB/layer, staging
// z-redundancy 2x -> 1.5x, interior stat atomics halve. Interior blocks
// 512 -> 256, grid 1024 -> 768. FMA order per output unchanged -> volumes
// bitwise identical. Mini path byte-identical to R22 (DZ=2, SRC0 dedup,
// live-col writes). absmax 4.0 lineage.

typedef unsigned short u16;
typedef unsigned int   u32;
using s16x8 = __attribute__((ext_vector_type(8))) short;
using f32x4 = __attribute__((ext_vector_type(4))) float;

#define IN_ELEMS 262144        // 128*128*16 fp32 interior
#define MN_ELEMS 4194304       // 128*128*16*16 u16 mini
#define WS_NEED  28508480ull

__device__ __forceinline__ float bf2f(u16 h) {
    union { u32 u; float f; } v; v.u = ((u32)h) << 16; return v.f;
}
__device__ __forceinline__ u16 f2bf(float f) {
    union { float f; u32 u; } v; v.f = f;
    u32 u = v.u;
    return (u16)((u + 0x7fffu + ((u >> 16) & 1u)) >> 16);
}
__device__ __forceinline__ float ldin(const void* p, int i, int bf) {
    return bf ? bf2f(((const u16*)p)[i]) : ((const float*)p)[i];
}
__device__ __forceinline__ u16 ldbf(const void* p, int i, int bf) {
    return bf ? ((const u16*)p)[i] : f2bf(((const float*)p)[i]);
}
__device__ __forceinline__ void unpack8(uint4 a, float* f) {
    u32 w[4] = {a.x, a.y, a.z, a.w};
#pragma unroll
    for (int i = 0; i < 4; i++) {
        f[2*i]   = bf2f((u16)(w[i] & 0xffff));
        f[2*i+1] = bf2f((u16)(w[i] >> 16));
    }
}
__device__ __forceinline__ void unpack4(uint2 a, float* f) {
    f[0] = bf2f((u16)(a.x & 0xffff)); f[1] = bf2f((u16)(a.x >> 16));
    f[2] = bf2f((u16)(a.y & 0xffff)); f[3] = bf2f((u16)(a.y >> 16));
}

// Sum the 8 contention-spread stat banks -> sA[0..15]=mean, sA[16..31]=rstd.
__device__ __forceinline__ void stat8(const float* __restrict__ stP, int tid,
                                      float* __restrict__ sA)
{
    const float inv = 1.f / 2097152.f;
    int c = tid & 15;
    float ssum = 0.f, qsum = 0.f;
#pragma unroll
    for (int b2 = 0; b2 < 8; b2++) {
        ssum += stP[b2 * 32 + c];
        qsum += stP[b2 * 32 + 16 + c];
    }
    float m = ssum * inv;
    sA[tid] = (tid < 16) ? m : rsqrtf(qsum * inv - m * m + 1e-5f);
}

__global__ void sentinel_k(u16* __restrict__ out, int n)
{
    int i = blockIdx.x * 256 + threadIdx.x;
    if (i < n) out[i] = 0x4640;
}

// ---------------------------------------------------------------------------
// One-shot weight prep. 55 blocks:
//  0..17  : afrag[L][fi][lane][8]  (4608 lane-frags, MFMA A operands)
//  18     : st zero + flag + biasf
//  19..54 : w2d[L][tap9][ci][co] kx-summed fp32
// ---------------------------------------------------------------------------
__global__ __launch_bounds__(256) void wprep_k(
    const void* __restrict__ w0, const void* __restrict__ w1,
    const void* __restrict__ w2, const void* __restrict__ w3,
    const void* __restrict__ b0, const void* __restrict__ b1,
    const void* __restrict__ b2, const void* __restrict__ b3,
    float* __restrict__ st, int* __restrict__ flag,
    float* __restrict__ biasf, float* __restrict__ w2d,
    u16* __restrict__ afrag)
{
    const int tid = threadIdx.x;
    const u16* pp = (const u16*)w0;
    int cnt = 0;
    for (int i = 0; i < 32; i++) {
        int e = (pp[2 * i] >> 7) & 0xFF;
        if (e >= 64 && e <= 130) cnt++;
    }
    const int bf = (cnt >= 24) ? 1 : 0;
    const void* WS[4] = {w0, w1, w2, w3};
    const void* BS[4] = {b0, b1, b2, b3};
    const int b = blockIdx.x;

    if (b < 18) {
        int gi = b * 256 + tid;               // < 4608
        int L = gi / 1152, r = gi - L * 1152;
        int fi = r >> 6, l = r & 63;
        int kzky = fi >> 1, grp = fi & 1;
        int kz = kzky / 3, ky = kzky % 3;
        int n = l & 15, g = l >> 4, h = g & 1, kxs = g >> 1;
        int kx = grp * 2 + kxs;
        u16 v[8];
#pragma unroll
        for (int e = 0; e < 8; e++) {
            int ci = h * 8 + e;
            v[e] = (kx <= 2) ? ldbf(WS[L], n * 432 + ci * 27 + kz * 9 + ky * 3 + kx, bf)
                             : (u16)0;
        }
#pragma unroll
        for (int e = 0; e < 8; e++) afrag[gi * 8 + e] = v[e];
    } else if (b == 18) {
        for (int i = tid; i < 1024; i += 256) st[i] = 0.f;
        if (tid == 0) *flag = bf;
        if (tid < 64) biasf[tid] = ldin(BS[tid >> 4], tid & 15, bf);
    } else {
        int gi = (b - 19) * 256 + tid;        // < 9216
        int L = gi / 2304, r = gi - L * 2304;
        int tap = r >> 8, ci = (r >> 4) & 15, co = r & 15;
        int kz = tap / 3, ky = tap % 3;
        float s = 0.f;
#pragma unroll
        for (int kx = 0; kx < 3; kx++)
            s += ldin(WS[L], (co * 16 + ci) * 27 + kz * 9 + ky * 3 + kx, bf);
        w2d[gi] = s;
    }
}

// ---------------------------------------------------------------------------
// Fused layer. Blocks 0..255: interior 2D conv, block=(d-quad, 16-y slice),
// DP=4. Blocks 256..767: mini MFMA conv, block=(z-pair, 16-y tile), DZ=2.
// SRC0: staging builds layer-0 state directly from proj (x-constant dedup).
// NORM: staging normalizes previous raw output (8-bank stats). RES: +proj.
// WXB: write XB. Mini output writes restricted to live cols {0..3,8..11}.
// ---------------------------------------------------------------------------
template <int SRC0, int NORM, int RES, int WXB>
__global__ __launch_bounds__(256) void layer_k(
    const float* __restrict__ Iin, const u16* __restrict__ Min,
    const void* __restrict__ proj, const float* __restrict__ stP,
    const int* __restrict__ flagp,
    const float* __restrict__ w2dL, const u16* __restrict__ afragL,
    const float* __restrict__ biasL,
    float* __restrict__ Iout, u16* __restrict__ Mout,
    float* __restrict__ IXB, u16* __restrict__ MXB,
    float* __restrict__ st_out)
{
    // interior: wsl 2304 f | pin 6*18*20=2160 f | sred 32 f | sA 32 f (18112 B)
    // mini:     stage 72*256 u16 (36864 B) | sred 32 f | sA 32 f (37120 B)
    __shared__ __align__(16) char smem_raw[37120];
    const int tid = threadIdx.x;
    const int bf = (SRC0 || RES) ? *flagp : 0;
    const int bank = (blockIdx.x & 7) * 32;

    if (blockIdx.x < 256) {
        float* smem = (float*)smem_raw;
        float* wsl  = smem;          // 2304
        float* pin  = smem + 2304;   // 2160 (rows padded to 20 for b128)
        float* sred = smem + 4464;   // 32
        float* sA   = smem + 4496;   // 32
        const int d0 = (blockIdx.x >> 3) * 4;
        const int yo = (blockIdx.x & 7) * 16;
        if (tid < 32) {
            sred[tid] = 0.f;
            if (NORM) stat8(stP, tid, sA);
        }
        for (int i = tid; i < 576; i += 256)
            *(float4*)(wsl + i * 4) = *(const float4*)(w2dL + i * 4);
        if (NORM) __syncthreads();           // sA ready before pin staging
        for (int i = tid; i < 1728; i += 256) {
            int p = i / 288, r = i - p * 288;
            int row = r >> 4, c = r & 15;
            int zz = d0 + p - 1, gy = yo + row - 1;
            float v = 0.f;
            if ((unsigned)zz < 128u && (unsigned)gy < 128u) {
                if (SRC0) {
                    v = ldin(proj, c * 16384 + zz * 128 + gy, bf);
                } else {
                    v = Iin[(zz * 128 + gy) * 16 + c];
                    if (NORM) {
                        float res = RES ? ldin(proj, c * 16384 + zz * 128 + gy, bf) : 0.f;
                        v = fmaxf((v - sA[c]) * sA[16 + c] + res, 0.f);
                    }
                    if (WXB && p >= 1 && p <= 4 && row >= 1 && row <= 16)
                        IXB[(zz * 128 + gy) * 16 + c] = v;
                }
            }
            pin[p * 360 + row * 20 + c] = v;
        }
        __syncthreads();

        const int c = tid & 15, yl = tid >> 4;   // 16 c x 16 y
        float s = 0.f, q = 0.f;
#pragma unroll
        for (int dz = 0; dz < 4; ++dz) {
            float acc = biasL[c];
#pragma unroll
            for (int kz = 0; kz < 3; kz++) {
#pragma unroll
                for (int ky = 0; ky < 3; ky++) {
                    const float4* rowb = (const float4*)(pin + (dz + kz) * 360 + (yl + ky) * 20);
                    const float* wrow = wsl + (kz * 3 + ky) * 256 + c;
#pragma unroll
                    for (int qd = 0; qd < 4; qd++) {
                        float4 vq = rowb[qd];
                        acc = fmaf(vq.x, wrow[(qd * 4 + 0) * 16], acc);
                        acc = fmaf(vq.y, wrow[(qd * 4 + 1) * 16], acc);
                        acc = fmaf(vq.z, wrow[(qd * 4 + 2) * 16], acc);
                        acc = fmaf(vq.w, wrow[(qd * 4 + 3) * 16], acc);
                    }
                }
            }
            Iout[((d0 + dz) * 128 + yo + yl) * 16 + c] = acc;
            s += acc;
            q = fmaf(acc, acc, q);
        }
        s += __shfl_xor(s, 16, 64); s += __shfl_xor(s, 32, 64);
        q += __shfl_xor(q, 16, 64); q += __shfl_xor(q, 32, 64);
        if ((tid & 63) < 16) {
            atomicAdd(&sred[c], s);
            atomicAdd(&sred[16 + c], q);
        }
        __syncthreads();
        if (tid < 32) atomicAdd(&st_out[bank + tid], 120.f * sred[tid]);
        return;
    }

    // ---------------- mini path (z-pair, 16-y tiles, DZ=2) ----------------
    u16*   stage = (u16*)smem_raw;                 // 72 rows x 512B
    float* sred  = (float*)(smem_raw + 36864);
    float* sA    = (float*)(smem_raw + 36992);
    const int mb = blockIdx.x - 256;               // 0..511
    const int z0 = (mb & 63) * 2;
    const int yt = mb >> 6;                        // 0..7
    const int l = tid & 63, w = tid >> 6;
    const int n = l & 15, g = l >> 4, h = g & 1, kxs = g >> 1;
    const int y0 = yt * 16 + w * 4;
    const int y0b = yt * 16;

    if (tid < 32) {
        sred[tid] = 0.f;
        if (NORM) stat8(stP, tid, sA);
    }
    if (NORM) __syncthreads();               // sA ready before staging

    if (SRC0) {
        // x-constant dedup: 144 (row,half) items; fan out to the on-cols.
        for (int i = tid; i < 144; i += 256) {
            int r = i >> 1, hh = i & 1;
            int plane = r / 18, yr = r - plane * 18;
            int gz = z0 + plane - 1, gy = y0b + yr - 1;
            uint4 v = make_uint4(0u, 0u, 0u, 0u);
            if (((unsigned)gz < 128u) & ((unsigned)gy < 128u)) {
                u32 pw[4];
#pragma unroll
                for (int j = 0; j < 4; j++) {
                    int c0 = hh * 8 + 2 * j;
                    u16 a  = f2bf(ldin(proj, c0 * 16384 + gz * 128 + gy, bf));
                    u16 b2 = f2bf(ldin(proj, (c0 + 1) * 16384 + gz * 128 + gy, bf));
                    pw[j] = (u32)a | ((u32)b2 << 16);
                }
                v = make_uint4(pw[0], pw[1], pw[2], pw[3]);
            }
            u16* rowp = stage + r * 256 + hh * 8;
            const uint4 z4 = make_uint4(0u, 0u, 0u, 0u);
#pragma unroll
            for (int x = 0; x < 16; x++) {
                bool on = (x <= 4) | (x == 7) | (x >= 8 && x < 12);
                *(uint4*)(rowp + (x << 4)) = on ? v : z4;
            }
        }
    } else {
        // Stage 72 rows (4 z-planes x 18 y-rows), 512B each.
        for (int i = tid; i < 2304; i += 256) {
            int r = i >> 5, px = i & 31;
            int plane = r / 18, yr = r - plane * 18;
            int gz = z0 + plane - 1, gy = y0b + yr - 1;
            uint4 v = make_uint4(0u, 0u, 0u, 0u);
            bool inb = ((unsigned)gz < 128u) & ((unsigned)gy < 128u);
            int x = px >> 1, hh = px & 1;
            bool realc = (x < 4) | (x >= 8 && x < 12);
            bool ghost = (x == 4) | (x == 7);
            if (inb & (realc | ghost)) {
                float f[8];
                if (realc) {
                    uint4 raw = *(const uint4*)(Min + (((gz << 7) + gy) << 8) + px * 8);
                    unpack8(raw, f);
                } else {
                    const float* ip = Iin + ((gz * 128 + gy) * 16 + hh * 8);
                    float4 a  = *(const float4*)(ip);
                    float4 b2 = *(const float4*)(ip + 4);
                    f[0] = a.x;  f[1] = a.y;  f[2] = a.z;  f[3] = a.w;
                    f[4] = b2.x; f[5] = b2.y; f[6] = b2.z; f[7] = b2.w;
                }
                float vals[8];
#pragma unroll
                for (int j = 0; j < 8; j++) {
                    int c = hh * 8 + j;
                    float res = RES ? ldin(proj, c * 16384 + gz * 128 + gy, bf) : 0.f;
                    vals[j] = fmaxf((f[j] - sA[c]) * sA[16 + c] + res, 0.f);
                }
                u32 pw[4];
#pragma unroll
                for (int j = 0; j < 4; j++)
                    pw[j] = (u32)f2bf(vals[2*j]) | ((u32)f2bf(vals[2*j+1]) << 16);
                v = make_uint4(pw[0], pw[1], pw[2], pw[3]);
            }
            if (WXB && (plane == 1 || plane == 2) && yr >= 1 && yr <= 16
                    && realc)                       // live cols only
                *(uint4*)(MXB + (((gz << 7) + gy) << 8) + px * 8) = v;
            *(uint4*)(stage + r * 256 + px * 8) = v;
        }
    }

    s16x8 af[18];
#pragma unroll
    for (int fi = 0; fi < 18; fi++)
        af[fi] = *(const s16x8*)(afragL + (fi * 64 + l) * 8);
    f32x4 binit = *(const f32x4*)(biasL + g * 4);
    __syncthreads();

    const int x0c = n + kxs - 1;
    const int x1c = x0c + 2;
    const bool v0ok = (unsigned)x0c < 16u;
    const bool v1ok = (unsigned)x1c < 16u;
    const bool nlive = (n < 4) | (n >= 8 && n < 12);   // live output cols

    const float inc = (((n >> 2) & 1) == 0) ? 1.f : 0.f;
    float sr[4] = {0.f, 0.f, 0.f, 0.f}, qr[4] = {0.f, 0.f, 0.f, 0.f};

    for (int dz = 0; dz < 2; ++dz) {
        const int zz = z0 + dz;
        f32x4 acc[4];
#pragma unroll
        for (int yl = 0; yl < 4; yl++) acc[yl] = binit;

#pragma unroll
        for (int kz = 0; kz < 3; kz++) {
#pragma unroll
            for (int yin = 0; yin < 6; yin++) {
                const u16* rowp = stage + ((dz + kz) * 18 + (w << 2) + yin) * 256 + h * 8;
                uint4 q0 = make_uint4(0u, 0u, 0u, 0u);
                uint4 q1 = make_uint4(0u, 0u, 0u, 0u);
                if (v0ok) q0 = *(const uint4*)(rowp + (x0c << 4));
                if (v1ok) q1 = *(const uint4*)(rowp + (x1c << 4));
                s16x8 f0 = __builtin_bit_cast(s16x8, q0);
                s16x8 f1 = __builtin_bit_cast(s16x8, q1);
#pragma unroll
                for (int ky = 0; ky < 3; ky++) {
                    const int yl = yin - ky;
                    if (yl >= 0 && yl < 4) {
                        acc[yl] = __builtin_amdgcn_mfma_f32_16x16x32_bf16(af[(kz * 3 + ky) * 2],     f0, acc[yl], 0, 0, 0);
                        acc[yl] = __builtin_amdgcn_mfma_f32_16x16x32_bf16(af[(kz * 3 + ky) * 2 + 1], f1, acc[yl], 0, 0, 0);
                    }
                }
            }
        }

#pragma unroll
        for (int yl = 0; yl < 4; yl++) {
            const int gy = y0 + yl;
            u32 lo = (u32)f2bf(acc[yl][0]) | ((u32)f2bf(acc[yl][1]) << 16);
            u32 hi = (u32)f2bf(acc[yl][2]) | ((u32)f2bf(acc[yl][3]) << 16);
            if (nlive)
                *(uint2*)(Mout + (((zz << 7) + gy) << 8) + (n << 4) + g * 4) = make_uint2(lo, hi);
#pragma unroll
            for (int r = 0; r < 4; r++) {
                sr[r] += inc * acc[yl][r];
                qr[r] = fmaf(inc * acc[yl][r], acc[yl][r], qr[r]);
            }
        }
    }

#pragma unroll
    for (int off = 1; off < 16; off <<= 1) {
#pragma unroll
        for (int r = 0; r < 4; r++) {
            sr[r] += __shfl_down(sr[r], off, 16);
            qr[r] += __shfl_down(qr[r], off, 16);
        }
    }
    __syncthreads();
    if (n == 0) {
#pragma unroll
        for (int r = 0; r < 4; r++) {
            atomicAdd(&sred[g * 4 + r], sr[r]);
            atomicAdd(&sred[16 + g * 4 + r], qr[r]);
        }
    }
    __syncthreads();
    if (tid < 32) atomicAdd(&st_out[bank + tid], sred[tid]);
}

// ---------------------------------------------------------------------------
// Merged forward projection: 128 blocks x 512 threads, one block per d-slice.
// ---------------------------------------------------------------------------
__global__ __launch_bounds__(512) void fproj_k(
    const float* __restrict__ I4, const float* __restrict__ IXB,
    const u16* __restrict__ M4, const u16* __restrict__ MXB,
    const float* __restrict__ stL, const int* __restrict__ flagp,
    void* __restrict__ out)
{
    __shared__ float sA[32];
    __shared__ float red[8][36];     // per-wave partials: 8j*4cc | PS 4cc
    __shared__ float fin[160];       // Pf[8][16] | PS[16] | P0[16]
    const int bf = *flagp;
    const int d = blockIdx.x;
    const int tid = threadIdx.x;
    if (tid < 32) stat8(stL, tid, sA);
    __syncthreads();

    const int wv = tid >> 6;
    const int cgrp = wv & 3, half = wv >> 2;
    const int yl = tid & 63, y = half * 64 + yl;
    const int c0 = cgrp * 4;

    float v2d[4], row[4];
    {
        const int e = (d * 128 + y) * 16 + c0;
        float4 a = *(const float4*)(I4 + e);
        float4 x = *(const float4*)(IXB + e);
        float ia[4] = {a.x, a.y, a.z, a.w};
        float xa[4] = {x.x, x.y, x.z, x.w};
#pragma unroll
        for (int cc = 0; cc < 4; cc++) {
            int c = c0 + cc;
            v2d[cc] = fmaxf((ia[cc] - sA[c]) * sA[16 + c] + xa[cc], 0.f);
            row[cc] = 120.f * v2d[cc];
        }
    }
    float colp[8][4];
#pragma unroll
    for (int j = 0; j < 8; j++) {
        const int m = (j < 4) ? j : j + 4;
        const int e = ((d * 128 + y) << 8) + (m << 4) + c0;
        float f4[4], fx[4];
        unpack4(*(const uint2*)(M4 + e), f4);
        unpack4(*(const uint2*)(MXB + e), fx);
#pragma unroll
        for (int cc = 0; cc < 4; cc++) {
            int c = c0 + cc;
            float v = fmaxf((f4[cc] - sA[c]) * sA[16 + c] + fx[cc], 0.f);
            row[cc] += v;
            colp[j][cc] = v;
        }
    }
    // theta = 0 output
#pragma unroll
    for (int cc = 0; cc < 4; cc++) {
        int oi = ((c0 + cc) * 2) * 16384 + d * 128 + y;
        if (bf) ((u16*)out)[oi] = f2bf(row[cc]); else ((float*)out)[oi] = row[cc];
    }
    // wave reduce over 64 y
#pragma unroll
    for (int off = 1; off < 64; off <<= 1) {
#pragma unroll
        for (int cc = 0; cc < 4; cc++) {
            v2d[cc] += __shfl_down(v2d[cc], off, 64);
#pragma unroll
            for (int j = 0; j < 8; j++)
                colp[j][cc] += __shfl_down(colp[j][cc], off, 64);
        }
    }
    if (yl == 0) {
#pragma unroll
        for (int j = 0; j < 8; j++)
#pragma unroll
            for (int cc = 0; cc < 4; cc++)
                red[wv][j * 4 + cc] = colp[j][cc];
#pragma unroll
        for (int cc = 0; cc < 4; cc++)
            red[wv][32 + cc] = v2d[cc];
    }
    __syncthreads();

    // combine halves
    if (tid < 160) {
        int t = tid;
        int c = t & 15, item = t >> 4;
        int w0 = c >> 2, cc = c & 3;
        float v;
        if (item < 8)       v = red[w0][item * 4 + cc] + red[4 + w0][item * 4 + cc];
        else if (item == 8) v = red[w0][32 + cc] + red[4 + w0][32 + cc];
        else                v = red[w0][0 * 4 + cc];
        fin[item < 8 ? item * 16 + c : (item == 8 ? 128 + c : 144 + c)] = v;
    }
    __syncthreads();

    // theta = pi/2 output
    for (int i = tid; i < 2048; i += 512) {
        int c = i >> 7, u = i & 127;
        float v;
        if (u == 0)        v = fin[144 + c];
        else if (u < 4)    v = fin[u * 16 + c];
        else if (u >= 124) v = fin[(u - 120) * 16 + c];
        else               v = fin[128 + c];
        int oi = (c * 2 + 1) * 16384 + d * 128 + u;
        if (bf) ((u16*)out)[oi] = f2bf(v); else ((float*)out)[oi] = v;
    }
}

extern "C" void kernel_launch(void* const* d_in, const int* in_sizes, int n_in,
                              void* d_out, int out_size, void* d_ws, size_t ws_size,
                              hipStream_t stream)
{
    if (ws_size < WS_NEED) {
        sentinel_k<<<(out_size + 255) / 256, 256, 0, stream>>>((u16*)d_out, out_size);
        return;
    }
    const void* proj = d_in[0];
    const void* w1 = d_in[1]; const void* b1 = d_in[2];
    const void* w2 = d_in[3]; const void* b2 = d_in[4];
    const void* w3 = d_in[5]; const void* b3 = d_in[6];
    const void* w4 = d_in[7]; const void* b4 = d_in[8];

    float* I_A  = (float*)d_ws;
    float* I_B  = I_A + IN_ELEMS;
    float* I_XB = I_B + IN_ELEMS;
    u16*   M_A  = (u16*)(I_XB + IN_ELEMS);
    u16*   M_B  = M_A + MN_ELEMS;
    u16*   M_XB = M_B + MN_ELEMS;
    float* st    = (float*)(M_XB + MN_ELEMS);   // 1024 (4 layers x 8 banks x 32)
    int*   flag  = (int*)(st + 1024);           // 16
    float* biasf = (float*)(flag + 16);         // 64
    float* w2d   = biasf + 64;                  // 9216
    u16*   afrag = (u16*)(w2d + 9216 + 20480);  // keep legacy offset

    wprep_k<<<55, 256, 0, stream>>>(w1, w2, w3, w4, b1, b2, b3, b4,
                                    st, flag, biasf, w2d, afrag);

    dim3 lg(768), cb(256);
    // L1: conv1 on vol0, built directly from proj (SRC0).   -> B, stats st0
    layer_k<1,0,0,0><<<lg, cb, 0, stream>>>(I_A, M_A, proj, st, flag,
                                            w2d + 0,    afrag + 0,     biasf + 0,
                                            I_B, M_B, nullptr, nullptr, st + 0);
    // L2: conv2 on relu(IN_st0(y1)).      B -> A, stats st1
    layer_k<0,1,0,0><<<lg, cb, 0, stream>>>(I_B, M_B, proj, st + 0, flag,
                                            w2d + 2304, afrag + 9216,  biasf + 16,
                                            I_A, M_A, nullptr, nullptr, st + 256);
    // L3: conv3 on XB=relu(IN_st1(y2)+proj); materialize XB.  A -> B, stats st2
    layer_k<0,1,1,1><<<lg, cb, 0, stream>>>(I_A, M_A, proj, st + 256, flag,
                                            w2d + 4608, afrag + 18432, biasf + 32,
                                            I_B, M_B, I_XB, M_XB, st + 512);
    // L4: conv4 on relu(IN_st2(y3)).      B -> A, stats st3
    layer_k<0,1,0,0><<<lg, cb, 0, stream>>>(I_B, M_B, proj, st + 512, flag,
                                            w2d + 6912, afrag + 27648, biasf + 48,
                                            I_A, M_A, nullptr, nullptr, st + 768);
    // merged projection: raw y4 in A, residual XB
    fproj_k<<<128, dim3(512), 0, stream>>>(I_A, I_XB, M_A, M_XB, st + 768, flag, d_out);
}

// Round 15
// 172.718 us; speedup vs baseline: 1.1218x; 1.1218x over previous
//
#include <hip/hip_runtime.h>

// GeometryTransformation: backproject(theta=0) -> 2x resblock(conv3d 16->16 3^3,
// InstanceNorm, ReLU, residual) -> forward-project at theta in {0, pi/2}.
//
// Round-24: revert to R22 (172.9us), the bracketed optimum of this
// decomposition. Knobs tested both directions with counters:
//   mini y-tile 8<16 (R17 +8us) | mini DZ 1<2>4 (R18/R20) | DP 1<2>4 (R21/R23)
//   coop persistent kernel: grid.sync >= boundary cost (R16: 488us)
// R22 config: DP=2 interior, DZ=2 mini, SRC0 x-constant staging dedup,
// dead-column write elimination, merged fproj. absmax 4.0 lineage.

typedef unsigned short u16;
typedef unsigned int   u32;
using s16x8 = __attribute__((ext_vector_type(8))) short;
using f32x4 = __attribute__((ext_vector_type(4))) float;

#define IN_ELEMS 262144        // 128*128*16 fp32 interior
#define MN_ELEMS 4194304       // 128*128*16*16 u16 mini
#define WS_NEED  28508480ull

__device__ __forceinline__ float bf2f(u16 h) {
    union { u32 u; float f; } v; v.u = ((u32)h) << 16; return v.f;
}
__device__ __forceinline__ u16 f2bf(float f) {
    union { float f; u32 u; } v; v.f = f;
    u32 u = v.u;
    return (u16)((u + 0x7fffu + ((u >> 16) & 1u)) >> 16);
}
__device__ __forceinline__ float ldin(const void* p, int i, int bf) {
    return bf ? bf2f(((const u16*)p)[i]) : ((const float*)p)[i];
}
__device__ __forceinline__ u16 ldbf(const void* p, int i, int bf) {
    return bf ? ((const u16*)p)[i] : f2bf(((const float*)p)[i]);
}
__device__ __forceinline__ void unpack8(uint4 a, float* f) {
    u32 w[4] = {a.x, a.y, a.z, a.w};
#pragma unroll
    for (int i = 0; i < 4; i++) {
        f[2*i]   = bf2f((u16)(w[i] & 0xffff));
        f[2*i+1] = bf2f((u16)(w[i] >> 16));
    }
}
__device__ __forceinline__ void unpack4(uint2 a, float* f) {
    f[0] = bf2f((u16)(a.x & 0xffff)); f[1] = bf2f((u16)(a.x >> 16));
    f[2] = bf2f((u16)(a.y & 0xffff)); f[3] = bf2f((u16)(a.y >> 16));
}

// Sum the 8 contention-spread stat banks -> sA[0..15]=mean, sA[16..31]=rstd.
__device__ __forceinline__ void stat8(const float* __restrict__ stP, int tid,
                                      float* __restrict__ sA)
{
    const float inv = 1.f / 2097152.f;
    int c = tid & 15;
    float ssum = 0.f, qsum = 0.f;
#pragma unroll
    for (int b2 = 0; b2 < 8; b2++) {
        ssum += stP[b2 * 32 + c];
        qsum += stP[b2 * 32 + 16 + c];
    }
    float m = ssum * inv;
    sA[tid] = (tid < 16) ? m : rsqrtf(qsum * inv - m * m + 1e-5f);
}

__global__ void sentinel_k(u16* __restrict__ out, int n)
{
    int i = blockIdx.x * 256 + threadIdx.x;
    if (i < n) out[i] = 0x4640;
}

// ---------------------------------------------------------------------------
// One-shot weight prep. 55 blocks:
//  0..17  : afrag[L][fi][lane][8]  (4608 lane-frags, MFMA A operands)
//  18     : st zero + flag + biasf
//  19..54 : w2d[L][tap9][ci][co] kx-summed fp32
// ---------------------------------------------------------------------------
__global__ __launch_bounds__(256) void wprep_k(
    const void* __restrict__ w0, const void* __restrict__ w1,
    const void* __restrict__ w2, const void* __restrict__ w3,
    const void* __restrict__ b0, const void* __restrict__ b1,
    const void* __restrict__ b2, const void* __restrict__ b3,
    float* __restrict__ st, int* __restrict__ flag,
    float* __restrict__ biasf, float* __restrict__ w2d,
    u16* __restrict__ afrag)
{
    const int tid = threadIdx.x;
    const u16* pp = (const u16*)w0;
    int cnt = 0;
    for (int i = 0; i < 32; i++) {
        int e = (pp[2 * i] >> 7) & 0xFF;
        if (e >= 64 && e <= 130) cnt++;
    }
    const int bf = (cnt >= 24) ? 1 : 0;
    const void* WS[4] = {w0, w1, w2, w3};
    const void* BS[4] = {b0, b1, b2, b3};
    const int b = blockIdx.x;

    if (b < 18) {
        int gi = b * 256 + tid;               // < 4608
        int L = gi / 1152, r = gi - L * 1152;
        int fi = r >> 6, l = r & 63;
        int kzky = fi >> 1, grp = fi & 1;
        int kz = kzky / 3, ky = kzky % 3;
        int n = l & 15, g = l >> 4, h = g & 1, kxs = g >> 1;
        int kx = grp * 2 + kxs;
        u16 v[8];
#pragma unroll
        for (int e = 0; e < 8; e++) {
            int ci = h * 8 + e;
            v[e] = (kx <= 2) ? ldbf(WS[L], n * 432 + ci * 27 + kz * 9 + ky * 3 + kx, bf)
                             : (u16)0;
        }
#pragma unroll
        for (int e = 0; e < 8; e++) afrag[gi * 8 + e] = v[e];
    } else if (b == 18) {
        for (int i = tid; i < 1024; i += 256) st[i] = 0.f;
        if (tid == 0) *flag = bf;
        if (tid < 64) biasf[tid] = ldin(BS[tid >> 4], tid & 15, bf);
    } else {
        int gi = (b - 19) * 256 + tid;        // < 9216
        int L = gi / 2304, r = gi - L * 2304;
        int tap = r >> 8, ci = (r >> 4) & 15, co = r & 15;
        int kz = tap / 3, ky = tap % 3;
        float s = 0.f;
#pragma unroll
        for (int kx = 0; kx < 3; kx++)
            s += ldin(WS[L], (co * 16 + ci) * 27 + kz * 9 + ky * 3 + kx, bf);
        w2d[gi] = s;
    }
}

// ---------------------------------------------------------------------------
// Fused layer. Blocks 0..511: interior 2D conv, block=(d-pair, 16-y slice),
// DP=2. Blocks 512..1023: mini MFMA conv, block=(z-pair, 16-y tile), DZ=2.
// SRC0: staging builds layer-0 state directly from proj (x-constant dedup).
// NORM: staging normalizes previous raw output (8-bank stats). RES: +proj.
// WXB: write XB. Mini output writes restricted to live cols {0..3,8..11}.
// ---------------------------------------------------------------------------
template <int SRC0, int NORM, int RES, int WXB>
__global__ __launch_bounds__(256) void layer_k(
    const float* __restrict__ Iin, const u16* __restrict__ Min,
    const void* __restrict__ proj, const float* __restrict__ stP,
    const int* __restrict__ flagp,
    const float* __restrict__ w2dL, const u16* __restrict__ afragL,
    const float* __restrict__ biasL,
    float* __restrict__ Iout, u16* __restrict__ Mout,
    float* __restrict__ IXB, u16* __restrict__ MXB,
    float* __restrict__ st_out)
{
    // interior: wsl 2304 f | pin 4*18*20=1440 f | sred 32 f | sA 32 f (15232 B)
    // mini:     stage 72*256 u16 (36864 B) | sred 32 f | sA 32 f (37120 B)
    __shared__ __align__(16) char smem_raw[37120];
    const int tid = threadIdx.x;
    const int bf = (SRC0 || RES) ? *flagp : 0;
    const int bank = (blockIdx.x & 7) * 32;

    if (blockIdx.x < 512) {
        float* smem = (float*)smem_raw;
        float* wsl  = smem;          // 2304
        float* pin  = smem + 2304;   // 1440 (rows padded to 20 for b128)
        float* sred = smem + 3744;   // 32
        float* sA   = smem + 3776;   // 32
        const int d0 = (blockIdx.x >> 3) * 2;
        const int yo = (blockIdx.x & 7) * 16;
        if (tid < 32) {
            sred[tid] = 0.f;
            if (NORM) stat8(stP, tid, sA);
        }
        for (int i = tid; i < 576; i += 256)
            *(float4*)(wsl + i * 4) = *(const float4*)(w2dL + i * 4);
        if (NORM) __syncthreads();           // sA ready before pin staging
        for (int i = tid; i < 1152; i += 256) {
            int p = i / 288, r = i - p * 288;
            int row = r >> 4, c = r & 15;
            int zz = d0 + p - 1, gy = yo + row - 1;
            float v = 0.f;
            if ((unsigned)zz < 128u && (unsigned)gy < 128u) {
                if (SRC0) {
                    v = ldin(proj, c * 16384 + zz * 128 + gy, bf);
                } else {
                    v = Iin[(zz * 128 + gy) * 16 + c];
                    if (NORM) {
                        float res = RES ? ldin(proj, c * 16384 + zz * 128 + gy, bf) : 0.f;
                        v = fmaxf((v - sA[c]) * sA[16 + c] + res, 0.f);
                    }
                    if (WXB && (p == 1 || p == 2) && row >= 1 && row <= 16)
                        IXB[(zz * 128 + gy) * 16 + c] = v;
                }
            }
            pin[p * 360 + row * 20 + c] = v;
        }
        __syncthreads();

        const int c = tid & 15, yl = tid >> 4;   // 16 c x 16 y
        float s = 0.f, q = 0.f;
#pragma unroll
        for (int dz = 0; dz < 2; ++dz) {
            float acc = biasL[c];
#pragma unroll
            for (int kz = 0; kz < 3; kz++) {
#pragma unroll
                for (int ky = 0; ky < 3; ky++) {
                    const float4* rowb = (const float4*)(pin + (dz + kz) * 360 + (yl + ky) * 20);
                    const float* wrow = wsl + (kz * 3 + ky) * 256 + c;
#pragma unroll
                    for (int qd = 0; qd < 4; qd++) {
                        float4 vq = rowb[qd];
                        acc = fmaf(vq.x, wrow[(qd * 4 + 0) * 16], acc);
                        acc = fmaf(vq.y, wrow[(qd * 4 + 1) * 16], acc);
                        acc = fmaf(vq.z, wrow[(qd * 4 + 2) * 16], acc);
                        acc = fmaf(vq.w, wrow[(qd * 4 + 3) * 16], acc);
                    }
                }
            }
            Iout[((d0 + dz) * 128 + yo + yl) * 16 + c] = acc;
            s += acc;
            q = fmaf(acc, acc, q);
        }
        s += __shfl_xor(s, 16, 64); s += __shfl_xor(s, 32, 64);
        q += __shfl_xor(q, 16, 64); q += __shfl_xor(q, 32, 64);
        if ((tid & 63) < 16) {
            atomicAdd(&sred[c], s);
            atomicAdd(&sred[16 + c], q);
        }
        __syncthreads();
        if (tid < 32) atomicAdd(&st_out[bank + tid], 120.f * sred[tid]);
        return;
    }

    // ---------------- mini path (z-pair, 16-y tiles, DZ=2) ----------------
    u16*   stage = (u16*)smem_raw;                 // 72 rows x 512B
    float* sred  = (float*)(smem_raw + 36864);
    float* sA    = (float*)(smem_raw + 36992);
    const int mb = blockIdx.x - 512;               // 0..511
    const int z0 = (mb & 63) * 2;
    const int yt = mb >> 6;                        // 0..7
    const int l = tid & 63, w = tid >> 6;
    const int n = l & 15, g = l >> 4, h = g & 1, kxs = g >> 1;
    const int y0 = yt * 16 + w * 4;
    const int y0b = yt * 16;

    if (tid < 32) {
        sred[tid] = 0.f;
        if (NORM) stat8(stP, tid, sA);
    }
    if (NORM) __syncthreads();               // sA ready before staging

    if (SRC0) {
        // x-constant dedup: 144 (row,half) items; fan out to the 10 on-cols.
        for (int i = tid; i < 144; i += 256) {
            int r = i >> 1, hh = i & 1;
            int plane = r / 18, yr = r - plane * 18;
            int gz = z0 + plane - 1, gy = y0b + yr - 1;
            uint4 v = make_uint4(0u, 0u, 0u, 0u);
            if (((unsigned)gz < 128u) & ((unsigned)gy < 128u)) {
                u32 pw[4];
#pragma unroll
                for (int j = 0; j < 4; j++) {
                    int c0 = hh * 8 + 2 * j;
                    u16 a  = f2bf(ldin(proj, c0 * 16384 + gz * 128 + gy, bf));
                    u16 b2 = f2bf(ldin(proj, (c0 + 1) * 16384 + gz * 128 + gy, bf));
                    pw[j] = (u32)a | ((u32)b2 << 16);
                }
                v = make_uint4(pw[0], pw[1], pw[2], pw[3]);
            }
            u16* rowp = stage + r * 256 + hh * 8;
            const uint4 z4 = make_uint4(0u, 0u, 0u, 0u);
#pragma unroll
            for (int x = 0; x < 16; x++) {
                bool on = (x <= 4) | (x == 7) | (x >= 8 && x < 12);
                *(uint4*)(rowp + (x << 4)) = on ? v : z4;
            }
        }
    } else {
        // Stage 72 rows (4 z-planes x 18 y-rows), 512B each.
        for (int i = tid; i < 2304; i += 256) {
            int r = i >> 5, px = i & 31;
            int plane = r / 18, yr = r - plane * 18;
            int gz = z0 + plane - 1, gy = y0b + yr - 1;
            uint4 v = make_uint4(0u, 0u, 0u, 0u);
            bool inb = ((unsigned)gz < 128u) & ((unsigned)gy < 128u);
            int x = px >> 1, hh = px & 1;
            bool realc = (x < 4) | (x >= 8 && x < 12);
            bool ghost = (x == 4) | (x == 7);
            if (inb & (realc | ghost)) {
                float f[8];
                if (realc) {
                    uint4 raw = *(const uint4*)(Min + (((gz << 7) + gy) << 8) + px * 8);
                    unpack8(raw, f);
                } else {
                    const float* ip = Iin + ((gz * 128 + gy) * 16 + hh * 8);
                    float4 a  = *(const float4*)(ip);
                    float4 b2 = *(const float4*)(ip + 4);
                    f[0] = a.x;  f[1] = a.y;  f[2] = a.z;  f[3] = a.w;
                    f[4] = b2.x; f[5] = b2.y; f[6] = b2.z; f[7] = b2.w;
                }
                float vals[8];
#pragma unroll
                for (int j = 0; j < 8; j++) {
                    int c = hh * 8 + j;
                    float res = RES ? ldin(proj, c * 16384 + gz * 128 + gy, bf) : 0.f;
                    vals[j] = fmaxf((f[j] - sA[c]) * sA[16 + c] + res, 0.f);
                }
                u32 pw[4];
#pragma unroll
                for (int j = 0; j < 4; j++)
                    pw[j] = (u32)f2bf(vals[2*j]) | ((u32)f2bf(vals[2*j+1]) << 16);
                v = make_uint4(pw[0], pw[1], pw[2], pw[3]);
            }
            if (WXB && (plane == 1 || plane == 2) && yr >= 1 && yr <= 16
                    && realc)                       // live cols only
                *(uint4*)(MXB + (((gz << 7) + gy) << 8) + px * 8) = v;
            *(uint4*)(stage + r * 256 + px * 8) = v;
        }
    }

    s16x8 af[18];
#pragma unroll
    for (int fi = 0; fi < 18; fi++)
        af[fi] = *(const s16x8*)(afragL + (fi * 64 + l) * 8);
    f32x4 binit = *(const f32x4*)(biasL + g * 4);
    __syncthreads();

    const int x0c = n + kxs - 1;
    const int x1c = x0c + 2;
    const bool v0ok = (unsigned)x0c < 16u;
    const bool v1ok = (unsigned)x1c < 16u;
    const bool nlive = (n < 4) | (n >= 8 && n < 12);   // live output cols

    const float inc = (((n >> 2) & 1) == 0) ? 1.f : 0.f;
    float sr[4] = {0.f, 0.f, 0.f, 0.f}, qr[4] = {0.f, 0.f, 0.f, 0.f};

    for (int dz = 0; dz < 2; ++dz) {
        const int zz = z0 + dz;
        f32x4 acc[4];
#pragma unroll
        for (int yl = 0; yl < 4; yl++) acc[yl] = binit;

#pragma unroll
        for (int kz = 0; kz < 3; kz++) {
#pragma unroll
            for (int yin = 0; yin < 6; yin++) {
                const u16* rowp = stage + ((dz + kz) * 18 + (w << 2) + yin) * 256 + h * 8;
                uint4 q0 = make_uint4(0u, 0u, 0u, 0u);
                uint4 q1 = make_uint4(0u, 0u, 0u, 0u);
                if (v0ok) q0 = *(const uint4*)(rowp + (x0c << 4));
                if (v1ok) q1 = *(const uint4*)(rowp + (x1c << 4));
                s16x8 f0 = __builtin_bit_cast(s16x8, q0);
                s16x8 f1 = __builtin_bit_cast(s16x8, q1);
#pragma unroll
                for (int ky = 0; ky < 3; ky++) {
                    const int yl = yin - ky;
                    if (yl >= 0 && yl < 4) {
                        acc[yl] = __builtin_amdgcn_mfma_f32_16x16x32_bf16(af[(kz * 3 + ky) * 2],     f0, acc[yl], 0, 0, 0);
                        acc[yl] = __builtin_amdgcn_mfma_f32_16x16x32_bf16(af[(kz * 3 + ky) * 2 + 1], f1, acc[yl], 0, 0, 0);
                    }
                }
            }
        }

#pragma unroll
        for (int yl = 0; yl < 4; yl++) {
            const int gy = y0 + yl;
            u32 lo = (u32)f2bf(acc[yl][0]) | ((u32)f2bf(acc[yl][1]) << 16);
            u32 hi = (u32)f2bf(acc[yl][2]) | ((u32)f2bf(acc[yl][3]) << 16);
            if (nlive)
                *(uint2*)(Mout + (((zz << 7) + gy) << 8) + (n << 4) + g * 4) = make_uint2(lo, hi);
#pragma unroll
            for (int r = 0; r < 4; r++) {
                sr[r] += inc * acc[yl][r];
                qr[r] = fmaf(inc * acc[yl][r], acc[yl][r], qr[r]);
            }
        }
    }

#pragma unroll
    for (int off = 1; off < 16; off <<= 1) {
#pragma unroll
        for (int r = 0; r < 4; r++) {
            sr[r] += __shfl_down(sr[r], off, 16);
            qr[r] += __shfl_down(qr[r], off, 16);
        }
    }
    __syncthreads();
    if (n == 0) {
#pragma unroll
        for (int r = 0; r < 4; r++) {
            atomicAdd(&sred[g * 4 + r], sr[r]);
            atomicAdd(&sred[16 + g * 4 + r], qr[r]);
        }
    }
    __syncthreads();
    if (tid < 32) atomicAdd(&st_out[bank + tid], sred[tid]);
}

// ---------------------------------------------------------------------------
// Merged forward projection: 128 blocks x 512 threads, one block per d-slice.
// ---------------------------------------------------------------------------
__global__ __launch_bounds__(512) void fproj_k(
    const float* __restrict__ I4, const float* __restrict__ IXB,
    const u16* __restrict__ M4, const u16* __restrict__ MXB,
    const float* __restrict__ stL, const int* __restrict__ flagp,
    void* __restrict__ out)
{
    __shared__ float sA[32];
    __shared__ float red[8][36];     // per-wave partials: 8j*4cc | PS 4cc
    __shared__ float fin[160];       // Pf[8][16] | PS[16] | P0[16]
    const int bf = *flagp;
    const int d = blockIdx.x;
    const int tid = threadIdx.x;
    if (tid < 32) stat8(stL, tid, sA);
    __syncthreads();

    const int wv = tid >> 6;
    const int cgrp = wv & 3, half = wv >> 2;
    const int yl = tid & 63, y = half * 64 + yl;
    const int c0 = cgrp * 4;

    float v2d[4], row[4];
    {
        const int e = (d * 128 + y) * 16 + c0;
        float4 a = *(const float4*)(I4 + e);
        float4 x = *(const float4*)(IXB + e);
        float ia[4] = {a.x, a.y, a.z, a.w};
        float xa[4] = {x.x, x.y, x.z, x.w};
#pragma unroll
        for (int cc = 0; cc < 4; cc++) {
            int c = c0 + cc;
            v2d[cc] = fmaxf((ia[cc] - sA[c]) * sA[16 + c] + xa[cc], 0.f);
            row[cc] = 120.f * v2d[cc];
        }
    }
    float colp[8][4];
#pragma unroll
    for (int j = 0; j < 8; j++) {
        const int m = (j < 4) ? j : j + 4;
        const int e = ((d * 128 + y) << 8) + (m << 4) + c0;
        float f4[4], fx[4];
        unpack4(*(const uint2*)(M4 + e), f4);
        unpack4(*(const uint2*)(MXB + e), fx);
#pragma unroll
        for (int cc = 0; cc < 4; cc++) {
            int c = c0 + cc;
            float v = fmaxf((f4[cc] - sA[c]) * sA[16 + c] + fx[cc], 0.f);
            row[cc] += v;
            colp[j][cc] = v;
        }
    }
    // theta = 0 output
#pragma unroll
    for (int cc = 0; cc < 4; cc++) {
        int oi = ((c0 + cc) * 2) * 16384 + d * 128 + y;
        if (bf) ((u16*)out)[oi] = f2bf(row[cc]); else ((float*)out)[oi] = row[cc];
    }
    // wave reduce over 64 y
#pragma unroll
    for (int off = 1; off < 64; off <<= 1) {
#pragma unroll
        for (int cc = 0; cc < 4; cc++) {
            v2d[cc] += __shfl_down(v2d[cc], off, 64);
#pragma unroll
            for (int j = 0; j < 8; j++)
                colp[j][cc] += __shfl_down(colp[j][cc], off, 64);
        }
    }
    if (yl == 0) {
#pragma unroll
        for (int j = 0; j < 8; j++)
#pragma unroll
            for (int cc = 0; cc < 4; cc++)
                red[wv][j * 4 + cc] = colp[j][cc];
#pragma unroll
        for (int cc = 0; cc < 4; cc++)
            red[wv][32 + cc] = v2d[cc];
    }
    __syncthreads();

    // combine halves
    if (tid < 160) {
        int t = tid;
        int c = t & 15, item = t >> 4;
        int w0 = c >> 2, cc = c & 3;
        float v;
        if (item < 8)       v = red[w0][item * 4 + cc] + red[4 + w0][item * 4 + cc];
        else if (item == 8) v = red[w0][32 + cc] + red[4 + w0][32 + cc];
        else                v = red[w0][0 * 4 + cc];
        fin[item < 8 ? item * 16 + c : (item == 8 ? 128 + c : 144 + c)] = v;
    }
    __syncthreads();

    // theta = pi/2 output
    for (int i = tid; i < 2048; i += 512) {
        int c = i >> 7, u = i & 127;
        float v;
        if (u == 0)        v = fin[144 + c];
        else if (u < 4)    v = fin[u * 16 + c];
        else if (u >= 124) v = fin[(u - 120) * 16 + c];
        else               v = fin[128 + c];
        int oi = (c * 2 + 1) * 16384 + d * 128 + u;
        if (bf) ((u16*)out)[oi] = f2bf(v); else ((float*)out)[oi] = v;
    }
}

extern "C" void kernel_launch(void* const* d_in, const int* in_sizes, int n_in,
                              void* d_out, int out_size, void* d_ws, size_t ws_size,
                              hipStream_t stream)
{
    if (ws_size < WS_NEED) {
        sentinel_k<<<(out_size + 255) / 256, 256, 0, stream>>>((u16*)d_out, out_size);
        return;
    }
    const void* proj = d_in[0];
    const void* w1 = d_in[1]; const void* b1 = d_in[2];
    const void* w2 = d_in[3]; const void* b2 = d_in[4];
    const void* w3 = d_in[5]; const void* b3 = d_in[6];
    const void* w4 = d_in[7]; const void* b4 = d_in[8];

    float* I_A  = (float*)d_ws;
    float* I_B  = I_A + IN_ELEMS;
    float* I_XB = I_B + IN_ELEMS;
    u16*   M_A  = (u16*)(I_XB + IN_ELEMS);
    u16*   M_B  = M_A + MN_ELEMS;
    u16*   M_XB = M_B + MN_ELEMS;
    float* st    = (float*)(M_XB + MN_ELEMS);   // 1024 (4 layers x 8 banks x 32)
    int*   flag  = (int*)(st + 1024);           // 16
    float* biasf = (float*)(flag + 16);         // 64
    float* w2d   = biasf + 64;                  // 9216
    u16*   afrag = (u16*)(w2d + 9216 + 20480);  // keep legacy offset

    wprep_k<<<55, 256, 0, stream>>>(w1, w2, w3, w4, b1, b2, b3, b4,
                                    st, flag, biasf, w2d, afrag);

    dim3 lg(1024), cb(256);
    // L1: conv1 on vol0, built directly from proj (SRC0).   -> B, stats st0
    layer_k<1,0,0,0><<<lg, cb, 0, stream>>>(I_A, M_A, proj, st, flag,
                                            w2d + 0,    afrag + 0,     biasf + 0,
                                            I_B, M_B, nullptr, nullptr, st + 0);
    // L2: conv2 on relu(IN_st0(y1)).      B -> A, stats st1
    layer_k<0,1,0,0><<<lg, cb, 0, stream>>>(I_B, M_B, proj, st + 0, flag,
                                            w2d + 2304, afrag + 9216,  biasf + 16,
                                            I_A, M_A, nullptr, nullptr, st + 256);
    // L3: conv3 on XB=relu(IN_st1(y2)+proj); materialize XB.  A -> B, stats st2
    layer_k<0,1,1,1><<<lg, cb, 0, stream>>>(I_A, M_A, proj, st + 256, flag,
                                            w2d + 4608, afrag + 18432, biasf + 32,
                                            I_B, M_B, I_XB, M_XB, st + 512);
    // L4: conv4 on relu(IN_st2(y3)).      B -> A, stats st3
    layer_k<0,1,0,0><<<lg, cb, 0, stream>>>(I_B, M_B, proj, st + 512, flag,
                                            w2d + 6912, afrag + 27648, biasf + 48,
                                            I_A, M_A, nullptr, nullptr, st + 768);
    // merged projection: raw y4 in A, residual XB
    fproj_k<<<128, dim3(512), 0, stream>>>(I_A, I_XB, M_A, M_XB, st + 768, flag, d_out);
}